// Round 1
// 120.203 us; speedup vs baseline: 1.0663x; 1.0663x over previous
//
#include <hip/hip_runtime.h>

typedef __attribute__((ext_vector_type(8))) __bf16 bf16x8;
typedef __attribute__((ext_vector_type(2))) __bf16 bf16x2;
typedef __attribute__((ext_vector_type(4))) float f32x4;
typedef __attribute__((ext_vector_type(4))) unsigned int u32x4;

#define AS1 __attribute__((address_space(1)))
#define AS3 __attribute__((address_space(3)))

__device__ __forceinline__ unsigned short f2b(float f) {
    union { float f; unsigned int u; } c; c.f = f;
    unsigned int r = c.u + 0x7fffu + ((c.u >> 16) & 1u);
    return (unsigned short)(r >> 16);
}

__device__ __forceinline__ unsigned int pack2(float a, float b) {
    bf16x2 t;
    t[0] = (__bf16)a;
    t[1] = (__bf16)b;
    return __builtin_bit_cast(unsigned int, t);
}

__device__ __forceinline__ void gload_lds16(const void* g, void* l) {
    __builtin_amdgcn_global_load_lds((const AS1 unsigned int*)g,
                                     (AS3 unsigned int*)l, 16, 0, 0);
}

// ------------- fp32 -> bf16 convert (both inputs, one launch) -------------
__global__ void cvt2_kernel(const float* __restrict__ in0,
                            unsigned short* __restrict__ out0, int n0,
                            const float* __restrict__ in1,
                            unsigned short* __restrict__ out1, int n1) {
    int i = blockIdx.x * blockDim.x + threadIdx.x;
    int stride = gridDim.x * blockDim.x;
    const int nt = n0 + n1;
    for (; i < nt; i += stride) {
        if (i < n0) {
            float4 v = reinterpret_cast<const float4*>(in0)[i];
            ushort4 o;
            o.x = f2b(v.x); o.y = f2b(v.y); o.z = f2b(v.z); o.w = f2b(v.w);
            reinterpret_cast<ushort4*>(out0)[i] = o;
        } else {
            const int j = i - n0;
            float4 v = reinterpret_cast<const float4*>(in1)[j];
            ushort4 o;
            o.x = f2b(v.x); o.y = f2b(v.y); o.z = f2b(v.z); o.w = f2b(v.w);
            reinterpret_cast<ushort4*>(out1)[j] = o;
        }
    }
}

// ---------------- QKV GEMM: C[8192][3072] = hs @ W^T + bias ----------------
// r7 structure (8 waves, 64x64 wave tiles, 256x128 block tile) but BK=32:
// 3 LDS buffers of 24KB = 72KB -> 2 blocks/CU -> 4 waves/SIMD so one
// block's MFMA clusters hide the other's barrier/vmcnt drains (r7 was
// 1 block/CU, 2 waves/SIMD, MfmaUtil 35% = latency-bound).
// 64B rows = 4x16B granules, XOR swizzle slot = g ^ ((row>>1)&3)
// (uniform 8 accesses/bank per ds_read_b128; verified lane->bank map).
__global__ __launch_bounds__(512, 4) void qkv_gemm(
    const unsigned short* __restrict__ A,
    const unsigned short* __restrict__ Bw,
    const float* __restrict__ bias,
    unsigned short* __restrict__ qb,
    unsigned short* __restrict__ kb,
    unsigned short* __restrict__ vb)
{
    __shared__ __align__(16) char smem[73728];  // 3 x (A 16K + B 8K)
    const int tid = threadIdx.x;
    const int lane = tid & 63, w = tid >> 6;     // 8 waves
    const int wm = w >> 1, wn = w & 1;
    const int wg = (blockIdx.x & 7) * 96 + (blockIdx.x >> 3);
    const int mt = wg / 24;
    const int nt = wg % 24;
    const int fr = lane & 15, kg = lane >> 4;

    // staging: 16 rows x 64B per gload; lane l -> row (l>>2), slot (l&3)
    const int sr = lane >> 2;
    const int g  = (lane & 3) ^ ((sr >> 1) & 3);   // pre-swizzled src granule
    const unsigned short* a_srcg = A  + (size_t)(mt * 256 + w * 16 + sr) * 1024 + g * 8;
    const unsigned short* b_srcg = Bw + (size_t)(nt * 128 + w * 16 + sr) * 1024 + g * 8;

    f32x4 acc[4][4] = {};
    const int pg = (kg ^ ((fr >> 1) & 3)) * 16;    // read-side slot
    const int aoffA = (wm * 64 + fr) * 64;
    const int boffB = (wn * 64 + fr) * 64;

#define STAGE_FULL(buf, kt) do {                                    \
    char* Sb_ = smem + (buf) * 24576 + w * 1024;                    \
    const size_t ko_ = (size_t)(kt) * 32;                           \
    gload_lds16(a_srcg + ko_,          Sb_);                        \
    gload_lds16(a_srcg + 131072 + ko_, Sb_ + 8192);                 \
    gload_lds16(b_srcg + ko_,          Sb_ + 16384);                \
} while (0)

#define MM(m_, n_) do {                                                        \
    acc[m_][n_] = __builtin_amdgcn_mfma_f32_16x16x32_bf16(                     \
        af[m_], bf[n_], acc[m_][n_], 0, 0, 0);                                 \
} while (0)

// 2 phases per K-32 step; P2's frag reads drain (lgkmcnt) BEFORE the
// phase barrier so next step's stage into this buffer is WAR-safe.
#define GT2(CUR, PRE, kt, DOSTAGE, WNSTR) do {                                 \
    const char* Ab_ = smem + (CUR) * 24576;                                    \
    const char* Bb_ = Ab_ + 16384;                                             \
    char* Sb_ = smem + (PRE) * 24576 + w * 1024;                               \
    const size_t ko_ = (size_t)((kt) + 2) * 32;                                \
    bf16x8 af[4], bf[4];                                                       \
    _Pragma("unroll")                                                          \
    for (int n = 0; n < 4; ++n)                                                \
        bf[n] = *reinterpret_cast<const bf16x8*>(Bb_ + boffB + n * 1024 + pg); \
    _Pragma("unroll")                                                          \
    for (int m = 0; m < 2; ++m)                                                \
        af[m] = *reinterpret_cast<const bf16x8*>(Ab_ + aoffA + m * 1024 + pg); \
    if (DOSTAGE) {                                                             \
        gload_lds16(a_srcg + ko_,          Sb_);                               \
        gload_lds16(a_srcg + 131072 + ko_, Sb_ + 8192);                        \
    }                                                                          \
    __builtin_amdgcn_s_barrier();                                              \
    asm volatile("s_waitcnt lgkmcnt(0)" ::: "memory");                         \
    __builtin_amdgcn_s_setprio(1);                                             \
    MM(0, 0); MM(0, 1); MM(0, 2); MM(0, 3);                                    \
    MM(1, 0); MM(1, 1); MM(1, 2); MM(1, 3);                                    \
    __builtin_amdgcn_s_setprio(0);                                             \
    _Pragma("unroll")                                                          \
    for (int m = 2; m < 4; ++m)                                                \
        af[m] = *reinterpret_cast<const bf16x8*>(Ab_ + aoffA + m * 1024 + pg); \
    if (DOSTAGE) {                                                             \
        gload_lds16(b_srcg + ko_, Sb_ + 16384);                                \
    }                                                                          \
    asm volatile("s_waitcnt vmcnt(" WNSTR ") lgkmcnt(0)" ::: "memory");        \
    __builtin_amdgcn_s_barrier();                                              \
    __builtin_amdgcn_s_setprio(1);                                             \
    MM(2, 0); MM(2, 1); MM(2, 2); MM(2, 3);                                    \
    MM(3, 0); MM(3, 1); MM(3, 2); MM(3, 3);                                    \
    __builtin_amdgcn_s_setprio(0);                                             \
} while (0)

    STAGE_FULL(0, 0);
    STAGE_FULL(1, 1);
    asm volatile("s_waitcnt vmcnt(3)" ::: "memory");
    __builtin_amdgcn_s_barrier();
#pragma unroll 1
    for (int it = 0; it < 10; ++it) {
        const int t0 = it * 3;
        GT2(0, 2, t0 + 0, 1, "3");
        GT2(1, 0, t0 + 1, 1, "3");
        GT2(2, 1, t0 + 2, 1, "3");
    }
    GT2(0, 2, 30, 0, "0");
    GT2(1, 0, 31, 0, "0");
    __syncthreads();

    const int sidx = nt >> 3;
    float bv[4];
#pragma unroll
    for (int n = 0; n < 4; ++n) bv[n] = bias[nt * 128 + wn * 64 + n * 16 + fr];

    unsigned short* Cs = (unsigned short*)smem;

    if (sidx < 2) {
        unsigned short* dstb = (sidx == 0) ? qb : kb;
        const float sc = (sidx == 0) ? 0.1803368801111f : 1.0f;
#pragma unroll
        for (int p = 0; p < 2; ++p) {
            if ((wm >> 1) == p) {
                const int r0 = (wm & 1) * 64;
#pragma unroll
                for (int m = 0; m < 4; ++m)
#pragma unroll
                    for (int n = 0; n < 4; ++n)
#pragma unroll
                        for (int r = 0; r < 4; ++r)
                            Cs[(r0 + m * 16 + kg * 4 + r) * 136 + wn * 64 + n * 16 + fr] =
                                f2b((acc[m][n][r] + bv[n]) * sc);
            }
            __syncthreads();
#pragma unroll
            for (int itc = 0; itc < 4; ++itc) {
                const int task = itc * 512 + tid;
                const int rl = task >> 4;
                const int i16 = task & 15;
                const int t = mt * 256 + p * 128 + rl;
                const int b_ = t >> 10, s = t & 1023;
                const int head = ((nt * 128 + i16 * 8) >> 6) & 15;
                u32x4 v = *reinterpret_cast<const u32x4*>(Cs + rl * 136 + i16 * 8);
                *reinterpret_cast<u32x4*>(
                    dstb + ((size_t)(b_ * 16 + head) * 1024 + s) * 64 + (i16 & 7) * 8) = v;
            }
            __syncthreads();
        }
    } else {
#pragma unroll
        for (int p = 0; p < 2; ++p) {
            if ((wm >> 1) == p) {
                const int r0 = (wm & 1) * 64;
#pragma unroll
                for (int m = 0; m < 4; ++m)
#pragma unroll
                    for (int n = 0; n < 4; ++n)
#pragma unroll
                        for (int j = 0; j < 2; ++j) {
                            unsigned int pk = pack2(acc[m][n][2 * j] + bv[n],
                                                    acc[m][n][2 * j + 1] + bv[n]);
                            *reinterpret_cast<unsigned int*>(
                                Cs + (wn * 64 + n * 16 + fr) * 136
                                   + r0 + m * 16 + kg * 4 + 2 * j) = pk;
                        }
            }
            __syncthreads();
#pragma unroll
            for (int itc = 0; itc < 4; ++itc) {
                const int task = itc * 512 + tid;
                const int c = task >> 4;
                const int i16 = task & 15;
                const int col = nt * 128 + c;
                const int head = (col >> 6) & 15;
                const int d = col & 63;
                const int b_ = (mt * 256) >> 10;
                const int s0 = (mt * 256 & 1023) + p * 128 + i16 * 8;
                u32x4 v = *reinterpret_cast<const u32x4*>(Cs + c * 136 + i16 * 8);
                *reinterpret_cast<u32x4*>(
                    vb + (size_t)((b_ * 16 + head) * 64 + d) * 1024 + s0) = v;
            }
            __syncthreads();
        }
    }
#undef STAGE_FULL
#undef GT2
#undef MM
}

// ---------------- flash attention (swapped QK^T, permuted-K LDS) ----------
// grid: 128 bh * 8 qtiles of 128 rows; block 256 (4 waves x 32 q). KVB=64,
// qf=2 -> ~120 live VGPR; __launch_bounds__(256,4) targets 4 waves/SIMD
// (4 blocks/CU, grid 1024 = exactly 4/CU) to hide barrier/exp latency
// (r13 showed LDS-traffic halving = null -> latency-bound).
#define KVB 64
__global__ __launch_bounds__(256, 4) void attn_kernel(
    const unsigned short* __restrict__ qb,
    const unsigned short* __restrict__ kb,
    const unsigned short* __restrict__ vb,
    float* __restrict__ out)
{
    __shared__ __align__(16) char asmem[32768];  // 2 bufs x (K 8K + V 8K)
    const int tid = threadIdx.x;
    const int lane = tid & 63, w = tid >> 6;
    // XCD-chunked swizzle: 1024 = 8 * 128 (bijective)
    const int wg = (blockIdx.x & 7) * 128 + (blockIdx.x >> 3);
    const int bh = wg >> 3;
    const int qt = wg & 7;
    const int b_ = bh >> 4, h_ = bh & 15;
    const int fr = lane & 15, kg = lane >> 4;

    const unsigned short* qp = qb + ((size_t)bh * 1024 + qt * 128) * 64;
    const unsigned short* kp = kb + (size_t)bh * 1024 * 64;
    const unsigned short* vp = vb + (size_t)bh * 64 * 1024;

    bf16x8 qfr[2][2];
#pragma unroll
    for (int qf = 0; qf < 2; ++qf) {
        const unsigned short* qr = qp + (w * 32 + qf * 16 + fr) * 64 + kg * 8;
        qfr[qf][0] = *reinterpret_cast<const bf16x8*>(qr);
        qfr[qf][1] = *reinterpret_cast<const bf16x8*>(qr + 32);
    }

    float m_q[2] = {-1e30f, -1e30f}, l_q[2] = {0.f, 0.f};
    f32x4 o_acc[2][4] = {};

    const int ksr = w * 8 + (lane >> 3);   // staging row within 32-row group
    const int kcb = (lane & 7) * 16;       // granule byte within 128B row

#define ASTAGE(buf, kvt) do {                                                  \
    const int kv0_ = (kvt) * KVB;                                              \
    char* Kb_ = asmem + (buf) * 16384 + w * 1024;                              \
    char* Vb_ = Kb_ + 8192;                                                    \
    _Pragma("unroll")                                                          \
    for (int i = 0; i < 2; ++i) {                                              \
        const int st = i * 32 + ksr;                                           \
        const int key = ((st >> 5) << 5) | (((st & 15) >> 2) << 3)             \
                      | (((st >> 4) & 1) << 2) | (st & 3);                     \
        const int scb = kcb ^ ((st & 7) << 4);                                 \
        gload_lds16(kp + (size_t)(kv0_ + key) * 64 + (scb >> 1),               \
                    Kb_ + i * 4096);                                           \
        const int d_ = i * 32 + ksr;                                           \
        const int svb = kcb ^ ((d_ & 7) << 4);                                 \
        gload_lds16(vp + (size_t)d_ * 1024 + kv0_ + (svb >> 1),                \
                    Vb_ + i * 4096);                                           \
    }                                                                          \
} while (0)

#define ACOMP(buf) do {                                                        \
    const char* Kb = asmem + (buf) * 16384;                                    \
    const char* Vb = Kb + 8192;                                                \
    f32x4 sacc[2][4] = {};                                                     \
    __builtin_amdgcn_s_setprio(1);                                             \
    _Pragma("unroll")                                                          \
    for (int jt = 0; jt < 4; ++jt) {                                           \
        _Pragma("unroll")                                                      \
        for (int ks = 0; ks < 2; ++ks) {                                       \
            const int cb = (ks * 64 + kg * 16) ^ ((fr & 7) << 4);              \
            bf16x8 kf = *reinterpret_cast<const bf16x8*>(                      \
                Kb + (jt * 16 + fr) * 128 + cb);                               \
            _Pragma("unroll")                                                  \
            for (int qf = 0; qf < 2; ++qf)                                     \
                sacc[qf][jt] = __builtin_amdgcn_mfma_f32_16x16x32_bf16(        \
                    kf, qfr[qf][ks], sacc[qf][jt], 0, 0, 0);                   \
        }                                                                      \
    }                                                                          \
    __builtin_amdgcn_s_setprio(0);                                             \
    unsigned int P2[2][4][2];                                                  \
    _Pragma("unroll")                                                          \
    for (int qf = 0; qf < 2; ++qf) {                                           \
        float mx = -1e30f;                                                     \
        _Pragma("unroll")                                                      \
        for (int jt = 0; jt < 4; ++jt) {                                       \
            float a = fmaxf(fmaxf(sacc[qf][jt][0], sacc[qf][jt][1]),           \
                            fmaxf(sacc[qf][jt][2], sacc[qf][jt][3]));          \
            mx = fmaxf(mx, a);                                                 \
        }                                                                      \
        mx = fmaxf(mx, __shfl_xor(mx, 16, 64));                                \
        mx = fmaxf(mx, __shfl_xor(mx, 32, 64));                                \
        if (__any(mx > m_q[qf] + 8.0f)) {                                      \
            const float mn = fmaxf(m_q[qf], mx);                               \
            const float corr = __builtin_amdgcn_exp2f(m_q[qf] - mn);           \
            m_q[qf] = mn;                                                      \
            l_q[qf] *= corr;                                                   \
            float cr[4];                                                       \
            _Pragma("unroll")                                                  \
            for (int r = 0; r < 4; ++r)                                        \
                cr[r] = __shfl(corr, kg * 4 + r, 64);                          \
            _Pragma("unroll")                                                  \
            for (int d0 = 0; d0 < 4; ++d0)                                     \
                _Pragma("unroll")                                              \
                for (int r = 0; r < 4; ++r) o_acc[qf][d0][r] *= cr[r];         \
        }                                                                      \
        const float mn_ = m_q[qf];                                             \
        float rs = 0.f;                                                        \
        _Pragma("unroll")                                                      \
        for (int jt = 0; jt < 4; ++jt) {                                       \
            float p0 = __builtin_amdgcn_exp2f(sacc[qf][jt][0] - mn_);          \
            float p1 = __builtin_amdgcn_exp2f(sacc[qf][jt][1] - mn_);          \
            float p2 = __builtin_amdgcn_exp2f(sacc[qf][jt][2] - mn_);          \
            float p3 = __builtin_amdgcn_exp2f(sacc[qf][jt][3] - mn_);          \
            rs += (p0 + p1) + (p2 + p3);                                       \
            P2[qf][jt][0] = pack2(p0, p1);                                     \
            P2[qf][jt][1] = pack2(p2, p3);                                     \
        }                                                                      \
        rs += __shfl_xor(rs, 16, 64);                                          \
        rs += __shfl_xor(rs, 32, 64);                                          \
        l_q[qf] += rs;                                                         \
    }                                                                          \
    __builtin_amdgcn_s_setprio(1);                                             \
    _Pragma("unroll")                                                          \
    for (int c = 0; c < 2; ++c) {                                              \
        bf16x8 pa[2];                                                          \
        _Pragma("unroll")                                                      \
        for (int qf = 0; qf < 2; ++qf) {                                       \
            u32x4 pw = { P2[qf][2 * c][0], P2[qf][2 * c][1],                   \
                         P2[qf][2 * c + 1][0], P2[qf][2 * c + 1][1] };         \
            pa[qf] = __builtin_bit_cast(bf16x8, pw);                           \
        }                                                                      \
        _Pragma("unroll")                                                      \
        for (int d0 = 0; d0 < 4; ++d0) {                                       \
            const int dd = d0 * 16 + fr;                                       \
            const int cbv = (c * 64 + kg * 16) ^ ((dd & 7) << 4);              \
            bf16x8 vf = *reinterpret_cast<const bf16x8*>(Vb + dd * 128 + cbv); \
            _Pragma("unroll")                                                  \
            for (int qf = 0; qf < 2; ++qf)                                     \
                o_acc[qf][d0] = __builtin_amdgcn_mfma_f32_16x16x32_bf16(       \
                    pa[qf], vf, o_acc[qf][d0], 0, 0, 0);                       \
        }                                                                      \
    }                                                                          \
    __builtin_amdgcn_s_setprio(0);                                             \
} while (0)

    ASTAGE(0, 0);
#pragma unroll 1
    for (int t = 0; t < 15; ++t) {
        ASTAGE((t + 1) & 1, t + 1);
        asm volatile("s_waitcnt vmcnt(4) lgkmcnt(0)" ::: "memory");
        __builtin_amdgcn_s_barrier();
        ACOMP(t & 1);
        asm volatile("s_waitcnt lgkmcnt(0)" ::: "memory");
        __builtin_amdgcn_s_barrier();
    }
    asm volatile("s_waitcnt vmcnt(0) lgkmcnt(0)" ::: "memory");
    __builtin_amdgcn_s_barrier();
    ACOMP(1);

    // epilogue: normalize and write fp32 out[t][h*64+d]
#pragma unroll
    for (int qf = 0; qf < 2; ++qf) {
        float linv[4];
#pragma unroll
        for (int r = 0; r < 4; ++r)
            linv[r] = 1.0f / __shfl(l_q[qf], kg * 4 + r, 64);
        const int trow = b_ * 1024 + qt * 128 + w * 32 + qf * 16;
#pragma unroll
        for (int d0 = 0; d0 < 4; ++d0) {
            const int c = h_ * 64 + d0 * 16 + fr;
#pragma unroll
            for (int r = 0; r < 4; ++r)
                out[(size_t)(trow + kg * 4 + r) * 1024 + c] = o_acc[qf][d0][r] * linv[r];
        }
    }
#undef ASTAGE
#undef ACOMP
}

extern "C" void kernel_launch(void* const* d_in, const int* in_sizes, int n_in,
                              void* d_out, int out_size, void* d_ws, size_t ws_size,
                              hipStream_t stream)
{
    const float* hs   = (const float*)d_in[0];
    const float* Wqkv = (const float*)d_in[1];
    const float* Bqkv = (const float*)d_in[2];
    float* out = (float*)d_out;

    char* ws = (char*)d_ws;
    unsigned short* hsb = (unsigned short*)(ws);                        // 16 MB
    unsigned short* wb  = (unsigned short*)(ws + (size_t)16 * 1048576); //  6 MB
    unsigned short* qb  = (unsigned short*)(ws + (size_t)22 * 1048576); // 16 MB
    unsigned short* kb  = (unsigned short*)(ws + (size_t)38 * 1048576); // 16 MB
    unsigned short* vb  = (unsigned short*)(ws + (size_t)54 * 1048576); // 16 MB

    cvt2_kernel<<<2048, 256, 0, stream>>>(hs, hsb, 8192 * 1024 / 4,
                                          Wqkv, wb, 3072 * 1024 / 4);
    qkv_gemm<<<768, 512, 0, stream>>>(hsb, wb, Bqkv, qb, kb, vb);
    attn_kernel<<<1024, 256, 0, stream>>>(qb, kb, vb, out);
}